// Round 14
// baseline (110.416 us; speedup 1.0000x reference)
//
#include <hip/hip_runtime.h>

#define BINS 10
#define ROWW 11   // thread-private LDS row stride (11 coprime 32 banks)
#define NTHR 256

typedef float f32x4 __attribute__((ext_vector_type(4)));  // native vec for nt-load

// ===== ELEM MATH: byte-for-byte from R2/R8/R10/R13 (PASSED absmax 0.0). The
// algebraically-equivalent z-form (R3-R7) fails on HW — do not reintroduce.
//
// Scatter: ds_add_f32 (no-return LDS float atomic) on a thread-private row.
// - hist passed by ARRAY REFERENCE so after inlining the atomic's base is the
//   __shared__ variable itself -> addrspace(3) statically known -> true
//   ds_add_f32. (R8 passed a generic float*: compiler emitted a flat-path
//   atomic, per-lane slow, 101us.)
// - no return value used -> no ds_read, no lgkmcnt chain (R9's 50us limiter).
// - replaces the 30-slot predicated register scatter (R13's biggest VALU cost).
__device__ __forceinline__ void ghm_elem(float x, float tt,
                                         unsigned long long& pk,
                                         float (&hist)[NTHR * ROWW], int rowbase) {
    float t = __expf(-fabsf(x));                 // e^{-|x|}
    float u = 1.f + t;
    float r = __builtin_amdgcn_rcpf(u);          // ~1ulp approx, ample slack
    float sig = (x >= 0.f) ? r : t * r;          // sigmoid(x), all ranges
    float d = sig - tt;
    int idx = (int)(fabsf(d) * 10.f);            // trunc (validated R8/R10)
    idx = idx < 9 ? idx : 9;
    pk += 1ull << (6 * idx);                     // packed counts, 6b/bin
    float bce = fmaxf(x, 0.f) - x * tt + __logf(u);  // log1p(e^{-|x|}) = log(u)
    __hip_atomic_fetch_add(&hist[rowbase + idx], bce,
                           __ATOMIC_RELAXED, __HIP_MEMORY_SCOPE_WORKGROUP);
}

__global__ __launch_bounds__(256) void ghm_pass1(
    const float* __restrict__ pred, const float* __restrict__ tgt,
    long long n, int nb,
    float* __restrict__ bsum, int* __restrict__ bcnt)
{
    __shared__ float hist[NTHR * ROWW];   // 11 KB thread-private rows
    __shared__ float rsum[4][BINS];
    __shared__ int   rcnt[4][BINS];

    const int tid  = threadIdx.x;
    const int lane = tid & 63;
    const int wave = tid >> 6;
    const int rowbase = tid * ROWW;

#pragma unroll
    for (int b = 0; b < BINS; ++b) hist[rowbase + b] = 0.f;  // own row only

    unsigned long long pk = 0;
    int c[BINS];
#pragma unroll
    for (int b = 0; b < BINS; ++b) c[b] = 0;

    const long long n4 = n >> 2;
    const f32x4* p4 = (const f32x4*)pred;
    const f32x4* t4 = (const f32x4*)tgt;

    // Chunked contiguous partition + NT loads (R13, proven +20%).
    const long long qpb = (n4 + nb - 1) / nb;
    const long long q0  = (long long)blockIdx.x * qpb;
    const long long q1  = (q0 + qpb < n4) ? (q0 + qpb) : n4;

    int chunk = 0;
    for (long long i = q0 + tid; i < q1; i += 512) {   // unroll x2
        f32x4 pa = __builtin_nontemporal_load(&p4[i]);
        f32x4 ta = __builtin_nontemporal_load(&t4[i]);
        const long long j = i + 256;
        f32x4 pb, tb;
        const bool has2 = (j < q1);
        if (has2) {
            pb = __builtin_nontemporal_load(&p4[j]);
            tb = __builtin_nontemporal_load(&t4[j]);
        }
        ghm_elem(pa.x, ta.x, pk, hist, rowbase);
        ghm_elem(pa.y, ta.y, pk, hist, rowbase);
        ghm_elem(pa.z, ta.z, pk, hist, rowbase);
        ghm_elem(pa.w, ta.w, pk, hist, rowbase);
        if (has2) {
            ghm_elem(pb.x, tb.x, pk, hist, rowbase);
            ghm_elem(pb.y, tb.y, pk, hist, rowbase);
            ghm_elem(pb.z, tb.z, pk, hist, rowbase);
            ghm_elem(pb.w, tb.w, pk, hist, rowbase);
        }
        if (++chunk == 7) {              // 8 elems/iter x7 = 56 <= 63 per field
            chunk = 0;
#pragma unroll
            for (int b = 0; b < BINS; ++b) c[b] += (int)((pk >> (6 * b)) & 63u);
            pk = 0;
        }
    }
    const long long tail0 = n4 << 2;     // n % 4 remainder: block 0
    if (blockIdx.x == 0 && (long long)tid < (n - tail0))
        ghm_elem(pred[tail0 + tid], tgt[tail0 + tid], pk, hist, rowbase);
#pragma unroll
    for (int b = 0; b < BINS; ++b) c[b] += (int)((pk >> (6 * b)) & 63u);

    // block reduce: own LDS row (same-thread ds ops are pipe-ordered; compiler
    // inserts the lgkmcnt before use) -> shuffle tree per bin (validated)
#pragma unroll
    for (int b = 0; b < BINS; ++b) {
        float v = hist[rowbase + b];
        int   k = c[b];
        for (int off = 32; off; off >>= 1) {
            v += __shfl_down(v, off);
            k += __shfl_down(k, off);
        }
        if (lane == 0) { rsum[wave][b] = v; rcnt[wave][b] = k; }
    }
    __syncthreads();
    if (tid < BINS) {
        int b = tid;
        float v = rsum[0][b] + rsum[1][b] + rsum[2][b] + rsum[3][b];
        int   k = rcnt[0][b] + rcnt[1][b] + rcnt[2][b] + rcnt[3][b];
        bsum[(long long)b * nb + blockIdx.x] = v;   // bin-major partials
        bcnt[(long long)b * nb + blockIdx.x] = k;
    }
}

// 10 waves, one bin per wave: parallel strided loads, shuffle reduce.
// Byte-for-byte validated since R2.
__global__ __launch_bounds__(640) void ghm_pass2(
    const float* __restrict__ bsum, const int* __restrict__ bcnt,
    int nb, float* __restrict__ out)
{
    __shared__ double    ssum[BINS];
    __shared__ long long scnt[BINS];
    const int lane = threadIdx.x & 63;
    const int wave = threadIdx.x >> 6;   // 0..9 == bin

    double    acc = 0.0;
    long long cc  = 0;
    for (int i = lane; i < nb; i += 64) {
        acc += (double)bsum[(long long)wave * nb + i];
        cc  += (long long)bcnt[(long long)wave * nb + i];
    }
    for (int off = 32; off; off >>= 1) {
        acc += __shfl_down(acc, off);
        cc  += __shfl_down(cc, off);
    }
    if (lane == 0) { ssum[wave] = acc; scnt[wave] = cc; }
    __syncthreads();

    if (threadIdx.x == 0) {
        int n = 0;
#pragma unroll
        for (int b = 0; b < BINS; ++b) n += (scnt[b] > 0) ? 1 : 0;
        double loss = 0.0;
        if (n > 0) {
#pragma unroll
            for (int b = 0; b < BINS; ++b)
                if (scnt[b] > 0)
                    loss += ssum[b] / ((double)scnt[b] * (double)n);
        }
        out[0] = (float)loss;
    }
}

extern "C" void kernel_launch(void* const* d_in, const int* in_sizes, int n_in,
                              void* d_out, int out_size, void* d_ws, size_t ws_size,
                              hipStream_t stream) {
    const float* pred = (const float*)d_in[0];
    const float* tgt  = (const float*)d_in[1];
    float* out = (float*)d_out;
    const long long n = (long long)in_sizes[0];

    int nb = 2048;
    const size_t per_block = (size_t)BINS * (sizeof(float) + sizeof(int)); // 80 B
    while (nb > 1 && (size_t)nb * per_block > ws_size) nb >>= 1;

    float* bsum = (float*)d_ws;
    int*   bcnt = (int*)((char*)d_ws + (size_t)nb * BINS * sizeof(float));

    ghm_pass1<<<nb, 256, 0, stream>>>(pred, tgt, n, nb, bsum, bcnt);
    ghm_pass2<<<1, 640, 0, stream>>>(bsum, bcnt, nb, out);
}

// Round 15
// 44.530 us; speedup vs baseline: 2.4796x; 2.4796x over previous
//
#include <hip/hip_runtime.h>
#include <hip/hip_fp16.h>

#define BINS 10

typedef float f32x4 __attribute__((ext_vector_type(4)));  // native vec for nt-load

__device__ __forceinline__ unsigned pk_add_f16x2(unsigned a, unsigned b) {
    __half2 ha = __builtin_bit_cast(__half2, a);
    __half2 hb = __builtin_bit_cast(__half2, b);
    return __builtin_bit_cast(unsigned, __hadd2(ha, hb));   // v_pk_add_f16
}

// ===== ELEM MATH: byte-for-byte from R2/R8/R13 (PASSED absmax 0.0). The
// algebraically-equivalent z-form (R3-R7) fails on HW — do not reintroduce.
//
// Scatter: packed-f16 PAIR accumulators in registers. 5 u32 regs hold 10 bins
// (2 per reg as __half2). Per elem: cvt_f16 + shift prep + 5x(cmp+cndmask+
// v_pk_add_f16) ~= 20 VALU slots, vs 30 for the 10-way f32 predicated scatter
// (R13's biggest VALU block). Flushed to f32 every 56 elems: worst-case window
// sum 56*5.7~320 << 65504; RNE rounding unbiased -> loss error ~1e-6.
// LDS atomics (R8/R14: 101us slow path) and volatile RMW chains (R9) banned.
__device__ __forceinline__ void ghm_elem(float x, float tt,
                                         unsigned long long& pk,
                                         unsigned (&acc)[5]) {
    float t = __expf(-fabsf(x));                 // e^{-|x|}
    float u = 1.f + t;
    float r = __builtin_amdgcn_rcpf(u);          // ~1ulp approx, ample slack
    float sig = (x >= 0.f) ? r : t * r;          // sigmoid(x), all ranges
    float d = sig - tt;
    int idx = (int)(fabsf(d) * 10.f);            // trunc (validated R8/R10)
    idx = idx < 9 ? idx : 9;
    pk += 1ull << (6 * idx);                     // packed counts, 6b/bin
    float bce = fmaxf(x, 0.f) - x * tt + __logf(u);  // log1p(e^{-|x|}) = log(u)
    unsigned hv = (unsigned)__builtin_bit_cast(unsigned short, __float2half(bce));
    hv <<= ((idx & 1) << 4);                     // place in low/high half
    const int pair = idx >> 1;
#pragma unroll
    for (int p = 0; p < 5; ++p)                  // cmp + cndmask + pk_add
        acc[p] = pk_add_f16x2(acc[p], (pair == p) ? hv : 0u);
}

__global__ __launch_bounds__(256) void ghm_pass1(
    const float* __restrict__ pred, const float* __restrict__ tgt,
    long long n, int nb,
    float* __restrict__ bsum, int* __restrict__ bcnt)
{
    __shared__ float rsum[4][BINS];
    __shared__ int   rcnt[4][BINS];

    const int tid  = threadIdx.x;
    const int lane = tid & 63;
    const int wave = tid >> 6;

    float s[BINS];
#pragma unroll
    for (int b = 0; b < BINS; ++b) s[b] = 0.f;
    unsigned acc[5];
#pragma unroll
    for (int p = 0; p < 5; ++p) acc[p] = 0u;
    unsigned long long pk = 0;
    int c[BINS];
#pragma unroll
    for (int b = 0; b < BINS; ++b) c[b] = 0;

    const long long n4 = n >> 2;
    const f32x4* p4 = (const f32x4*)pred;
    const f32x4* t4 = (const f32x4*)tgt;

    // Chunked contiguous partition + NT loads (R13, proven 51->40us).
    const long long qpb = (n4 + nb - 1) / nb;
    const long long q0  = (long long)blockIdx.x * qpb;
    const long long q1  = (q0 + qpb < n4) ? (q0 + qpb) : n4;

    int chunk = 0;
    for (long long i = q0 + tid; i < q1; i += 512) {   // unroll x2
        f32x4 pa = __builtin_nontemporal_load(&p4[i]);
        f32x4 ta = __builtin_nontemporal_load(&t4[i]);
        const long long j = i + 256;
        f32x4 pb, tb;
        const bool has2 = (j < q1);
        if (has2) {
            pb = __builtin_nontemporal_load(&p4[j]);
            tb = __builtin_nontemporal_load(&t4[j]);
        }
        ghm_elem(pa.x, ta.x, pk, acc);
        ghm_elem(pa.y, ta.y, pk, acc);
        ghm_elem(pa.z, ta.z, pk, acc);
        ghm_elem(pa.w, ta.w, pk, acc);
        if (has2) {
            ghm_elem(pb.x, tb.x, pk, acc);
            ghm_elem(pb.y, tb.y, pk, acc);
            ghm_elem(pb.z, tb.z, pk, acc);
            ghm_elem(pb.w, tb.w, pk, acc);
        }
        if (++chunk == 7) {   // 56 elems: 6-bit count fields <=63, f16 sums <=~320
            chunk = 0;
#pragma unroll
            for (int b = 0; b < BINS; ++b) c[b] += (int)((pk >> (6 * b)) & 63u);
            pk = 0;
#pragma unroll
            for (int p = 0; p < 5; ++p) {
                __half2 h = __builtin_bit_cast(__half2, acc[p]);
                s[2 * p]     += __half2float(__low2half(h));
                s[2 * p + 1] += __half2float(__high2half(h));
                acc[p] = 0u;
            }
        }
    }
    const long long tail0 = n4 << 2;     // n % 4 remainder: block 0
    if (blockIdx.x == 0 && (long long)tid < (n - tail0))
        ghm_elem(pred[tail0 + tid], tgt[tail0 + tid], pk, acc);
#pragma unroll
    for (int b = 0; b < BINS; ++b) c[b] += (int)((pk >> (6 * b)) & 63u);
#pragma unroll
    for (int p = 0; p < 5; ++p) {
        __half2 h = __builtin_bit_cast(__half2, acc[p]);
        s[2 * p]     += __half2float(__low2half(h));
        s[2 * p + 1] += __half2float(__high2half(h));
    }

    // block reduce: shuffle tree per bin, then cross-wave via LDS (validated)
#pragma unroll
    for (int b = 0; b < BINS; ++b) {
        float v = s[b];
        int   k = c[b];
        for (int off = 32; off; off >>= 1) {
            v += __shfl_down(v, off);
            k += __shfl_down(k, off);
        }
        if (lane == 0) { rsum[wave][b] = v; rcnt[wave][b] = k; }
    }
    __syncthreads();
    if (tid < BINS) {
        int b = tid;
        float v = rsum[0][b] + rsum[1][b] + rsum[2][b] + rsum[3][b];
        int   k = rcnt[0][b] + rcnt[1][b] + rcnt[2][b] + rcnt[3][b];
        bsum[(long long)b * nb + blockIdx.x] = v;   // bin-major partials
        bcnt[(long long)b * nb + blockIdx.x] = k;
    }
}

// 10 waves, one bin per wave: parallel strided loads, shuffle reduce.
// Byte-for-byte validated since R2.
__global__ __launch_bounds__(640) void ghm_pass2(
    const float* __restrict__ bsum, const int* __restrict__ bcnt,
    int nb, float* __restrict__ out)
{
    __shared__ double    ssum[BINS];
    __shared__ long long scnt[BINS];
    const int lane = threadIdx.x & 63;
    const int wave = threadIdx.x >> 6;   // 0..9 == bin

    double    acc = 0.0;
    long long cc  = 0;
    for (int i = lane; i < nb; i += 64) {
        acc += (double)bsum[(long long)wave * nb + i];
        cc  += (long long)bcnt[(long long)wave * nb + i];
    }
    for (int off = 32; off; off >>= 1) {
        acc += __shfl_down(acc, off);
        cc  += __shfl_down(cc, off);
    }
    if (lane == 0) { ssum[wave] = acc; scnt[wave] = cc; }
    __syncthreads();

    if (threadIdx.x == 0) {
        int n = 0;
#pragma unroll
        for (int b = 0; b < BINS; ++b) n += (scnt[b] > 0) ? 1 : 0;
        double loss = 0.0;
        if (n > 0) {
#pragma unroll
            for (int b = 0; b < BINS; ++b)
                if (scnt[b] > 0)
                    loss += ssum[b] / ((double)scnt[b] * (double)n);
        }
        out[0] = (float)loss;
    }
}

extern "C" void kernel_launch(void* const* d_in, const int* in_sizes, int n_in,
                              void* d_out, int out_size, void* d_ws, size_t ws_size,
                              hipStream_t stream) {
    const float* pred = (const float*)d_in[0];
    const float* tgt  = (const float*)d_in[1];
    float* out = (float*)d_out;
    const long long n = (long long)in_sizes[0];

    int nb = 2048;
    const size_t per_block = (size_t)BINS * (sizeof(float) + sizeof(int)); // 80 B
    while (nb > 1 && (size_t)nb * per_block > ws_size) nb >>= 1;

    float* bsum = (float*)d_ws;
    int*   bcnt = (int*)((char*)d_ws + (size_t)nb * BINS * sizeof(float));

    ghm_pass1<<<nb, 256, 0, stream>>>(pred, tgt, n, nb, bsum, bcnt);
    ghm_pass2<<<1, 640, 0, stream>>>(bsum, bcnt, nb, out);
}